// Round 1
// baseline (885.503 us; speedup 1.0000x reference)
//
#include <hip/hip_runtime.h>

// ReLU-RNN B=8192, T=1024, I=7, H=100, O=1 — barrier-free MFMA recurrence.
//
// v2: TWO independent 16-row batch tiles per wave (A,B). The W' fragments
// (112 VGPRs) are shared; each tile adds only hf[4]+acc[7]+xv[4][4].
// Rationale: at 1 wave/SIMD there is no TLP — ~50% of each step was exposed
// MFMA/VALU dependency latency (MfmaUtil 23.5%, VALUBusy 28%, occ 6%).
// Interleaving two tiles' 14 independent kt-chains fills those stalls.
// Grid: 256 blocks x 64 threads = 1 wave/CU.
//
// Repack v2: pack-then-packed-relu. cvt_pkrtz(neg) stays negative, so
// v_pk_max_f16(x,0) after the pack is bit-identical to fmax-before-pack
// under RTZ. Halves repack VALU for kt=0..2. hf[3]'s x/bias lanes are NOT
// relu'd (x can be negative) — kept on the scalar fmax path for the h part.
//
// Permuted-index scheme unchanged from v1:
//   D position (ti, q, r) [n' = 16ti+4q+r, batch m = lane&15] maps to
//   B slot k' = 32kt + 8q + jj ; kt=3,jj>=4 slots carry x0..x6 and bias.

typedef _Float16 half8 __attribute__((ext_vector_type(8)));
typedef float f32x4 __attribute__((ext_vector_type(4)));
typedef unsigned u32x4 __attribute__((ext_vector_type(4)));

static __device__ __forceinline__ unsigned pkrtz(float a, float b) {
    return __builtin_bit_cast(unsigned, __builtin_amdgcn_cvt_pkrtz(a, b));
}

__global__ __launch_bounds__(64, 1)
void rnn_wave(const float* __restrict__ x,
              const float* __restrict__ W_ih,
              const float* __restrict__ W_hh,
              const float* __restrict__ b_ih,
              const float* __restrict__ b_hh,
              const float* __restrict__ W_fc,
              const float* __restrict__ b_fc,
              float* __restrict__ out) {
    const int l  = threadIdx.x;
    const int lm = l & 15;           // batch row within tile
    const int q  = l >> 4;           // quad
    const bool q1   = (q == 1);
    const bool qlt2 = (q < 2);

    // ---- W' fragments (constant for all 1024 steps; 7 tiles x 4 kt) ----
    half8 w[7][4];
#pragma unroll
    for (int ti = 0; ti < 7; ++ti) {
        const int np = 16 * ti + lm;                  // output row n'
#pragma unroll
        for (int kt = 0; kt < 4; ++kt) {
            half8 hw;
#pragma unroll
            for (int jj = 0; jj < 8; ++jj) {
                float v = 0.f;
                if (np < 100) {
                    if (jj < 4) {                     // h slot, p = 16kt+4q+jj
                        int p = 16 * kt + 4 * q + jj;
                        if (p < 100) v = W_hh[np * 100 + p];
                    } else if (kt < 3) {              // h slot, p = 16(kt+4)+4q+(jj-4)
                        int p = 16 * (kt + 4) + 4 * q + (jj - 4);
                        if (p < 100) v = W_hh[np * 100 + p];
                    } else {                          // kt==3, jj>=4: x / bias slots
                        if (q == 0)      v = W_ih[np * 7 + (jj - 4)];      // x0..x3
                        else if (q == 1) v = (jj < 7) ? W_ih[np * 7 + jj]  // x4..x6
                                             : (b_ih[np] + b_hh[np]);     // bias @ jj=7
                    }
                }
                hw[jj] = (_Float16)v;
            }
            w[ti][kt] = hw;
        }
    }

    // ---- x addressing: two row tiles, lane loads only the dwords it supplies
    const float* xrA = x + (size_t)(blockIdx.x * 32 + lm) * 7168;
    const float* xrB = xrA + (size_t)16 * 7168;
    const int o0 = q1 ? 4 : 0, o1 = o0 + 1, o2 = o0 + 2, o3 = q1 ? 6 : 3;

    const u32x4 zz = {0u, 0u, 0u, 0u};
    const half8 hz = __builtin_bit_cast(half8, zz);

    // hfrag for t=0: h=0 everywhere, x_0/bias in kt=3 tail
    half8 hfA[4], hfB[4];
    {
        float a0 = xrA[o0], a1 = xrA[o1], a2 = xrA[o2], a3 = xrA[o3];
        float c0 = xrB[o0], c1 = xrB[o1], c2 = xrB[o2], c3 = xrB[o3];
        hfA[0] = hz; hfA[1] = hz; hfA[2] = hz;
        hfB[0] = hz; hfB[1] = hz; hfB[2] = hz;
        unsigned ad0 = pkrtz(a0, a1), ad1 = pkrtz(a2, q1 ? 1.0f : a3);
        unsigned bd0 = pkrtz(c0, c1), bd1 = pkrtz(c2, q1 ? 1.0f : c3);
        if (!qlt2) { ad0 = 0u; ad1 = 0u; bd0 = 0u; bd1 = 0u; }
        u32x4 ha = {0u, 0u, ad0, ad1};
        u32x4 hb = {0u, 0u, bd0, bd1};
        hfA[3] = __builtin_bit_cast(half8, ha);
        hfB[3] = __builtin_bit_cast(half8, hb);
    }

    // depth-4 x prefetch: slot s&3 holds x_s (only q<2 lanes consume x)
    float xvA[4][4], xvB[4][4];
    if (qlt2) {
#pragma unroll
        for (int s = 1; s <= 4; ++s) {
            const float* pA = xrA + s * 7;
            xvA[s & 3][0] = pA[o0]; xvA[s & 3][1] = pA[o1];
            xvA[s & 3][2] = pA[o2]; xvA[s & 3][3] = pA[o3];
            const float* pB = xrB + s * 7;
            xvB[s & 3][0] = pB[o0]; xvB[s & 3][1] = pB[o1];
            xvB[s & 3][2] = pB[o2]; xvB[s & 3][3] = pB[o3];
        }
    }

    const f32x4 kZ = {0.f, 0.f, 0.f, 0.f};
    f32x4 accA[7], accB[7];

    for (int tb = 0; tb < 1024; tb += 4) {
#pragma unroll
        for (int u = 0; u < 4; ++u) {
            const int t = tb + u;

            // 56 MFMAs; A/B tiles interleaved -> 14 independent chains per kt.
#pragma unroll
            for (int kt = 0; kt < 4; ++kt) {
                const int order[7] = {0, 4, 1, 5, 2, 6, 3};
#pragma unroll
                for (int oi = 0; oi < 7; ++oi) {
                    const int ti = order[oi];
                    accA[ti] = __builtin_amdgcn_mfma_f32_16x16x32_f16(
                        w[ti][kt], hfA[kt], (kt == 0) ? kZ : accA[ti], 0, 0, 0);
                    accB[ti] = __builtin_amdgcn_mfma_f32_16x16x32_f16(
                        w[ti][kt], hfB[kt], (kt == 0) ? kZ : accB[ti], 0, 0, 0);
                }
            }

            // in-register repack: D -> next B fragment (pack, then packed relu)
            const int s = (u + 1) & 3;
#pragma unroll
            for (int kt = 0; kt < 3; ++kt) {
                u32x4 da, db;
                da.x = pkrtz(accA[kt][0],     accA[kt][1]);
                da.y = pkrtz(accA[kt][2],     accA[kt][3]);
                da.z = pkrtz(accA[kt + 4][0], accA[kt + 4][1]);
                da.w = pkrtz(accA[kt + 4][2], accA[kt + 4][3]);
                hfA[kt] = __builtin_elementwise_max(__builtin_bit_cast(half8, da), hz);
                db.x = pkrtz(accB[kt][0],     accB[kt][1]);
                db.y = pkrtz(accB[kt][2],     accB[kt][3]);
                db.z = pkrtz(accB[kt + 4][0], accB[kt + 4][1]);
                db.w = pkrtz(accB[kt + 4][2], accB[kt + 4][3]);
                hfB[kt] = __builtin_elementwise_max(__builtin_bit_cast(half8, db), hz);
            }
            {
                unsigned ad0 = pkrtz(xvA[s][0], xvA[s][1]);
                unsigned ad1 = pkrtz(xvA[s][2], q1 ? 1.0f : xvA[s][3]);
                unsigned bd0 = pkrtz(xvB[s][0], xvB[s][1]);
                unsigned bd1 = pkrtz(xvB[s][2], q1 ? 1.0f : xvB[s][3]);
                if (!qlt2) { ad0 = 0u; ad1 = 0u; bd0 = 0u; bd1 = 0u; }
                u32x4 da, db;
                da.x = pkrtz(fmaxf(accA[3][0], 0.f), fmaxf(accA[3][1], 0.f));
                da.y = pkrtz(fmaxf(accA[3][2], 0.f), fmaxf(accA[3][3], 0.f));
                da.z = ad0; da.w = ad1;
                db.x = pkrtz(fmaxf(accB[3][0], 0.f), fmaxf(accB[3][1], 0.f));
                db.y = pkrtz(fmaxf(accB[3][2], 0.f), fmaxf(accB[3][3], 0.f));
                db.z = bd0; db.w = bd1;
                hfA[3] = __builtin_bit_cast(half8, da);
                hfB[3] = __builtin_bit_cast(half8, db);
            }

            // refill slot s with x_{t+5} (used 4 steps from now)
            int tn = t + 5; if (tn > 1023) tn = 1023;
            if (qlt2) {
                const float* pA = xrA + tn * 7;
                xvA[s][0] = pA[o0]; xvA[s][1] = pA[o1];
                xvA[s][2] = pA[o2]; xvA[s][3] = pA[o3];
                const float* pB = xrB + tn * 7;
                xvB[s][0] = pB[o0]; xvB[s][1] = pB[o1];
                xvB[s][2] = pB[o2]; xvB[s][3] = pB[o3];
            }
        }
    }

    // ---- epilogue: acc holds pre-relu h_T (permuted space, batch = lm) ----
    float sumA = 0.f, sumB = 0.f;
#pragma unroll
    for (int ti = 0; ti < 7; ++ti) {
#pragma unroll
        for (int r = 0; r < 4; ++r) {
            const int np = 16 * ti + 4 * q + r;
            const float wf = (np < 100) ? W_fc[np] : 0.f;
            sumA += wf * fmaxf(accA[ti][r], 0.f);
            sumB += wf * fmaxf(accB[ti][r], 0.f);
        }
    }
    sumA += __shfl_xor(sumA, 16, 64);   // reduce across the 4 q-lanes of row lm
    sumA += __shfl_xor(sumA, 32, 64);
    sumB += __shfl_xor(sumB, 16, 64);
    sumB += __shfl_xor(sumB, 32, 64);
    if (q == 0) {
        out[blockIdx.x * 32 + lm]      = sumA + b_fc[0];
        out[blockIdx.x * 32 + 16 + lm] = sumB + b_fc[0];
    }
}

extern "C" void kernel_launch(void* const* d_in, const int* in_sizes, int n_in,
                              void* d_out, int out_size, void* d_ws, size_t ws_size,
                              hipStream_t stream) {
    const float* x    = (const float*)d_in[0];
    const float* W_ih = (const float*)d_in[1];
    const float* W_hh = (const float*)d_in[2];
    const float* b_ih = (const float*)d_in[3];
    const float* b_hh = (const float*)d_in[4];
    const float* W_fc = (const float*)d_in[5];
    const float* b_fc = (const float*)d_in[6];
    float* out = (float*)d_out;

    rnn_wave<<<dim3(256), dim3(64), 0, stream>>>(x, W_ih, W_hh, b_ih, b_hh, W_fc, b_fc, out);
}

// Round 2
// 670.817 us; speedup vs baseline: 1.3200x; 1.3200x over previous
//
#include <hip/hip_runtime.h>

// ReLU-RNN B=8192, T=1024, I=7, H=100, O=1 — barrier-free MFMA recurrence.
//
// v3: revert to ONE 16-row tile per wave (512 waves, 1/SIMD). v2 proved the
// runtime is steps x per-wave-step-latency (waves are free; hardware is
// idle either way), and that per-step time is ~56% instruction-issue for a
// lone wave (I~560cy, L~450cy from the v1/v2 solve). So v3 minimizes the
// per-step instruction stream:
//   - x loads: one global_load_dwordx4 per step (was 4 scalar dwords);
//     per-q component select folded into 4 cndmasks at refill time.
//     q0 loads at t*7+0 -> (x0..x3); q1 at t*7+3 -> (x3..x6), uses .yzw + 1.0
//     (max addr 7167, never OOB). q2/q3 load at +0: their hf[3] tail words
//     multiply ZERO weight rows, so garbage (finite) x is harmless.
//   - pack-then-packed-relu (v_pk_max_f16 after cvt_pkrtz; bit-exact under
//     RTZ, verified by v2 pass) for kt=0..2: 12 -> 8 VALU each.
//   - no per-step lane zeroing (was 4 cndmask/step in v1).
// ~75 instr/step vs v1's ~110.
//
// Permuted-index scheme unchanged:
//   D position (ti, q, r) [n' = 16ti+4q+r, batch m = lane&15] maps to
//   B slot k' = 32kt + 8q + jj ; kt=3,jj>=4 slots carry x0..x6 and bias.

typedef _Float16 half8 __attribute__((ext_vector_type(8)));
typedef float f32x4 __attribute__((ext_vector_type(4)));
typedef unsigned u32x4 __attribute__((ext_vector_type(4)));

static __device__ __forceinline__ unsigned pkrtz(float a, float b) {
    return __builtin_bit_cast(unsigned, __builtin_amdgcn_cvt_pkrtz(a, b));
}

// 4-byte-aligned float4 load (x rows have stride 7 floats; t*7 is odd-dword)
static __device__ __forceinline__ f32x4 ld4(const float* p) {
    typedef f32x4 __attribute__((aligned(4))) f32x4a;
    return *(const f32x4a*)p;
}

__global__ __launch_bounds__(64, 1)
void rnn_wave(const float* __restrict__ x,
              const float* __restrict__ W_ih,
              const float* __restrict__ W_hh,
              const float* __restrict__ b_ih,
              const float* __restrict__ b_hh,
              const float* __restrict__ W_fc,
              const float* __restrict__ b_fc,
              float* __restrict__ out) {
    const int l  = threadIdx.x;
    const int lm = l & 15;           // batch row within tile
    const int q  = l >> 4;           // quad
    const bool q1 = (q == 1);

    // ---- W' fragments (constant for all 1024 steps; 7 tiles x 4 kt) ----
    half8 w[7][4];
#pragma unroll
    for (int ti = 0; ti < 7; ++ti) {
        const int np = 16 * ti + lm;                  // output row n'
#pragma unroll
        for (int kt = 0; kt < 4; ++kt) {
            half8 hw;
#pragma unroll
            for (int jj = 0; jj < 8; ++jj) {
                float v = 0.f;
                if (np < 100) {
                    if (jj < 4) {                     // h slot, p = 16kt+4q+jj
                        int p = 16 * kt + 4 * q + jj;
                        if (p < 100) v = W_hh[np * 100 + p];
                    } else if (kt < 3) {              // h slot, p = 16(kt+4)+4q+(jj-4)
                        int p = 16 * (kt + 4) + 4 * q + (jj - 4);
                        if (p < 100) v = W_hh[np * 100 + p];
                    } else {                          // kt==3, jj>=4: x / bias slots
                        if (q == 0)      v = W_ih[np * 7 + (jj - 4)];      // x0..x3
                        else if (q == 1) v = (jj < 7) ? W_ih[np * 7 + jj]  // x4..x6
                                             : (b_ih[np] + b_hh[np]);     // bias @ jj=7
                        // q>=2: stays 0 — their hf[3] tail is don't-care
                    }
                }
                hw[jj] = (_Float16)v;
            }
            w[ti][kt] = hw;
        }
    }

    // ---- x addressing: one dwordx4 per step per lane ----
    const float* xr = x + (size_t)(blockIdx.x * 16 + lm) * 7168;
    const int xo = q1 ? 3 : 0;       // q1 reads (x3,x4,x5,x6); others (x0..x3)

    const u32x4 zz = {0u, 0u, 0u, 0u};
    const half8 hz = __builtin_bit_cast(half8, zz);

    // hfrag for t=0: h=0 everywhere, x_0/bias in kt=3 tail
    half8 hf[4];
    {
        f32x4 v = ld4(xr + xo);
        float x0 = q1 ? v.y : v.x, x1 = q1 ? v.z : v.y;
        float x2 = q1 ? v.w : v.z, x3 = q1 ? 1.0f : v.w;
        hf[0] = hz; hf[1] = hz; hf[2] = hz;
        u32x4 h3 = {0u, 0u, pkrtz(x0, x1), pkrtz(x2, x3)};
        hf[3] = __builtin_bit_cast(half8, h3);
    }

    // depth-4 x prefetch: slot s&3 holds x_s, component-selected at refill
    float xv[4][4];
#pragma unroll
    for (int s = 1; s <= 4; ++s) {
        f32x4 v = ld4(xr + s * 7 + xo);
        xv[s & 3][0] = q1 ? v.y : v.x;
        xv[s & 3][1] = q1 ? v.z : v.y;
        xv[s & 3][2] = q1 ? v.w : v.z;
        xv[s & 3][3] = q1 ? 1.0f : v.w;
    }

    const f32x4 kZ = {0.f, 0.f, 0.f, 0.f};
    f32x4 acc[7];

    for (int tb = 0; tb < 1024; tb += 4) {
#pragma unroll
        for (int u = 0; u < 4; ++u) {
            const int t = tb + u;

            // 28 MFMAs; chains spaced 7 apart. Order {0,4,1,5,2,6,3} so the
            // chains feeding hf[0] (acc0/acc4) retire earliest.
#pragma unroll
            for (int kt = 0; kt < 4; ++kt) {
                const int order[7] = {0, 4, 1, 5, 2, 6, 3};
#pragma unroll
                for (int oi = 0; oi < 7; ++oi) {
                    const int ti = order[oi];
                    acc[ti] = __builtin_amdgcn_mfma_f32_16x16x32_f16(
                        w[ti][kt], hf[kt], (kt == 0) ? kZ : acc[ti], 0, 0, 0);
                }
            }

            // in-register repack: D -> next B fragment (pack, then packed relu)
            const int s = (u + 1) & 3;
#pragma unroll
            for (int kt = 0; kt < 3; ++kt) {
                u32x4 d;
                d.x = pkrtz(acc[kt][0],     acc[kt][1]);
                d.y = pkrtz(acc[kt][2],     acc[kt][3]);
                d.z = pkrtz(acc[kt + 4][0], acc[kt + 4][1]);
                d.w = pkrtz(acc[kt + 4][2], acc[kt + 4][3]);
                hf[kt] = __builtin_elementwise_max(__builtin_bit_cast(half8, d), hz);
            }
            {
                // kt=3: h part needs relu; x/bias words must pass through raw
                u32x4 d;
                d.x = pkrtz(fmaxf(acc[3][0], 0.f), fmaxf(acc[3][1], 0.f));
                d.y = pkrtz(fmaxf(acc[3][2], 0.f), fmaxf(acc[3][3], 0.f));
                d.z = pkrtz(xv[s][0], xv[s][1]);
                d.w = pkrtz(xv[s][2], xv[s][3]);
                hf[3] = __builtin_bit_cast(half8, d);
            }

            // refill slot s with x_{t+5} (used 4 steps from now)
            int tn = t + 5; if (tn > 1023) tn = 1023;
            {
                f32x4 v = ld4(xr + tn * 7 + xo);
                xv[s][0] = q1 ? v.y : v.x;
                xv[s][1] = q1 ? v.z : v.y;
                xv[s][2] = q1 ? v.w : v.z;
                xv[s][3] = q1 ? 1.0f : v.w;
            }
        }
    }

    // ---- epilogue: acc holds pre-relu h_T (permuted space, batch = lm) ----
    float sum = 0.f;
#pragma unroll
    for (int ti = 0; ti < 7; ++ti) {
#pragma unroll
        for (int r = 0; r < 4; ++r) {
            const int np = 16 * ti + 4 * q + r;
            const float wf = (np < 100) ? W_fc[np] : 0.f;
            sum += wf * fmaxf(acc[ti][r], 0.f);
        }
    }
    sum += __shfl_xor(sum, 16, 64);   // reduce across the 4 q-lanes of row lm
    sum += __shfl_xor(sum, 32, 64);
    if (q == 0) out[blockIdx.x * 16 + lm] = sum + b_fc[0];
}

extern "C" void kernel_launch(void* const* d_in, const int* in_sizes, int n_in,
                              void* d_out, int out_size, void* d_ws, size_t ws_size,
                              hipStream_t stream) {
    const float* x    = (const float*)d_in[0];
    const float* W_ih = (const float*)d_in[1];
    const float* W_hh = (const float*)d_in[2];
    const float* b_ih = (const float*)d_in[3];
    const float* b_hh = (const float*)d_in[4];
    const float* W_fc = (const float*)d_in[5];
    const float* b_fc = (const float*)d_in[6];
    float* out = (float*)d_out;

    rnn_wave<<<dim3(512), dim3(64), 0, stream>>>(x, W_ih, W_hh, b_ih, b_hh, W_fc, b_fc, out);
}